// Round 1
// 566.905 us; speedup vs baseline: 1.0250x; 1.0250x over previous
//
#include <hip/hip_runtime.h>
#include <hip/hip_bf16.h>
#include <math.h>

// Problem constants (B,S,H,D fixed by the reference setup_inputs)
#define SLEN 2048
#define NH   12
#define NB   2
#define DH   64
#define IT   64          // i-rows per block
#define JT   64          // j-cols per tile
#define NWAVE 4
#define LDP  72          // P-buffer row stride (bf16 elems); 72*2B keeps 16B align

typedef __bf16 bfx8 __attribute__((ext_vector_type(8)));
typedef float  f32x4 __attribute__((ext_vector_type(4)));

// ---------------- pass 1: rotary + bf16 cast + V transpose ----------------
__global__ __launch_bounds__(256)
void ddit_prep(const float* __restrict__ qkv,
               const float* __restrict__ cosb,
               const float* __restrict__ sinb,
               __bf16* __restrict__ Qr, __bf16* __restrict__ Kr,
               __bf16* __restrict__ Vt)
{
    __shared__ __align__(16) __bf16 Vlds[64 * LDP];
    const int tid = threadIdx.x;
    const int nS  = SLEN / 64;
    const int s0  = (blockIdx.x % nS) * 64;
    const int bh  = blockIdx.x / nS;
    const int h   = bh % NH;
    const int b   = bh / NH;
    const int r   = tid >> 2;          // 0..63 row (s offset)
    const int d0  = (tid & 3) * 16;    // 16 d per thread
    const int s   = s0 + r;

#pragma unroll
    for (int t = 0; t < 2; ++t) {
        const float* src = qkv + (((size_t)((size_t)b * SLEN + s) * 3 + t) * NH + h) * DH;
        const float* cs  = cosb + ((size_t)s * 3 + t) * DH;
        const float* sn  = sinb + ((size_t)s * 3 + t) * DH;
        union { __bf16 hv[16]; uint4 u4[2]; } pk;
#pragma unroll
        for (int dd = 0; dd < 16; dd += 4) {
            const int d = d0 + dd;
            float4 f  = *(const float4*)(src + d);
            float4 g  = *(const float4*)(src + (d ^ 32));
            float4 c4 = *(const float4*)(cs + d);
            float4 s4 = *(const float4*)(sn + d);
            const float sg = (d < 32) ? -1.f : 1.f;
            pk.hv[dd + 0] = (__bf16)(f.x * c4.x + sg * g.x * s4.x);
            pk.hv[dd + 1] = (__bf16)(f.y * c4.y + sg * g.y * s4.y);
            pk.hv[dd + 2] = (__bf16)(f.z * c4.z + sg * g.z * s4.z);
            pk.hv[dd + 3] = (__bf16)(f.w * c4.w + sg * g.w * s4.w);
        }
        __bf16* dst = (t == 0 ? Qr : Kr) + ((size_t)bh * SLEN + s) * DH + d0;
        *(uint4*)(dst + 0) = pk.u4[0];
        *(uint4*)(dst + 8) = pk.u4[1];
    }

    {
        const float* src = qkv + (((size_t)((size_t)b * SLEN + s) * 3 + 2) * NH + h) * DH;
#pragma unroll
        for (int dd = 0; dd < 16; dd += 4) {
            float4 f = *(const float4*)(src + d0 + dd);
            union { __bf16 hv[4]; uint2 u; } pk;
            pk.hv[0] = (__bf16)f.x; pk.hv[1] = (__bf16)f.y;
            pk.hv[2] = (__bf16)f.z; pk.hv[3] = (__bf16)f.w;
            *(uint2*)(Vlds + r * LDP + d0 + dd) = pk.u;
        }
    }
    __syncthreads();
    {
        const int dv   = tid >> 2;
        const int soff = (tid & 3) * 16;
        union { __bf16 hv[16]; uint4 u4[2]; } pk;
#pragma unroll
        for (int j = 0; j < 16; ++j)
            pk.hv[j] = Vlds[(soff + j) * LDP + dv];
        __bf16* dst = Vt + ((size_t)bh * DH + dv) * SLEN + s0 + soff;
        *(uint4*)(dst + 0) = pk.u4[0];
        *(uint4*)(dst + 8) = pk.u4[1];
    }
}

// ---------------- pass 2: barrier-free fused attention (swapped QK^T) ----------------
// mfma(K,Q): D[col=lane&15 = q-row i][row=(lane>>4)*4+reg = j-local].
// Each lane owns ONE q-row (i = m) with 4 consecutive j per reg quad:
//   -> float4 nontemporal logits stores (4 instrs/tile instead of 16 scalar)
//   -> per-lane softmax state; row reduce = 2 shfl_xor (16,32) instead of 4x(4+4)
//   -> P staged as 4x 8B ds_writes
__global__ __launch_bounds__(256)
void ddit_attn(const __bf16* __restrict__ Qr,
               const __bf16* __restrict__ Kr,
               const __bf16* __restrict__ Vt,
               const int*   __restrict__ seqlens,
               float* __restrict__ out_x,
               float* __restrict__ out_logits)
{
    __shared__ __align__(16) __bf16 Pbuf[NWAVE * 16 * LDP]; // per-wave, no barrier needed

    const int tid  = threadIdx.x;
    const int wave = tid >> 6;
    const int lane = tid & 63;
    const int qd   = lane >> 4;   // quad 0..3
    const int m    = lane & 15;

    // XCD swizzle: keep all 32 i-blocks of one bh on the same XCD (L2 locality)
    const int nIt   = SLEN / IT;                    // 32
    const int gridN = NB * NH * nIt;                // 768
    const int bid   = blockIdx.x;
    const int nid   = (bid & 7) * (gridN >> 3) + (bid >> 3);
    const int it    = nid % nIt;
    const int bh    = nid / nIt;
    const int b     = bh / NH;
    const int i0    = it * IT;
    const int len   = seqlens[b];

    const __bf16* Qb = Qr + (size_t)bh * SLEN * DH;
    const __bf16* Kb = Kr + (size_t)bh * SLEN * DH;
    const __bf16* Vb = Vt + (size_t)bh * DH * SLEN;

    const int iG_lane = i0 + wave * 16 + m;       // this lane's q-row
    float* lrow = out_logits + (size_t)bh * SLEN * SLEN + (size_t)iG_lane * SLEN;
    __bf16* myP = Pbuf + wave * 16 * LDP;

    f32x4 acc[4];
#pragma unroll
    for (int c = 0; c < 4; ++c) acc[c] = (f32x4){0.f, 0.f, 0.f, 0.f};
    const f32x4 NEG4 = (f32x4){-1.0e10f, -1.0e10f, -1.0e10f, -1.0e10f};

    // ---- fast path: fully padded i-block ----
    // All logits -1e10; reference softmax over an all-masked row is uniform,
    // so x = mean over ALL 2048 v rows. Do PV with P==1, skip K/QK/softmax.
    if (i0 >= len) {
        union { __bf16 h[4]; uint2 u; } ones;
#pragma unroll
        for (int r = 0; r < 4; ++r) ones.h[r] = (__bf16)1.0f;
#pragma unroll
        for (int t4 = 0; t4 < 4; ++t4)
            *(uint2*)(myP + m * LDP + t4 * 16 + qd * 4) = ones.u;
        bfx8 pf1[2];
#pragma unroll
        for (int kc = 0; kc < 2; ++kc)
            pf1[kc] = *(const bfx8*)&myP[m * LDP + kc * 32 + qd * 8];

        for (int j0 = 0; j0 < SLEN; j0 += JT) {
            bfx8 vf[2][4];
#pragma unroll
            for (int kc = 0; kc < 2; ++kc)
#pragma unroll
                for (int c = 0; c < 4; ++c)
                    vf[kc][c] = *(const bfx8*)(Vb + (size_t)(c * 16 + m) * SLEN + j0 + kc * 32 + qd * 8);
#pragma unroll
            for (int t4 = 0; t4 < 4; ++t4)
                __builtin_nontemporal_store(NEG4, (f32x4*)(lrow + j0 + t4 * 16 + qd * 4));
#pragma unroll
            for (int kc = 0; kc < 2; ++kc)
#pragma unroll
                for (int c = 0; c < 4; ++c)
                    acc[c] = __builtin_amdgcn_mfma_f32_16x16x32_bf16(pf1[kc], vf[kc][c], acc[c], 0, 0, 0);
        }
        const float inv = 1.0f / (float)SLEN;
#pragma unroll
        for (int r = 0; r < 4; ++r) {
            const int iG = i0 + wave * 16 + qd * 4 + r;
#pragma unroll
            for (int c = 0; c < 4; ++c)
                out_x[((size_t)bh * SLEN + iG) * DH + c * 16 + m] = acc[c][r] * inv;
        }
        return;
    }

    // ---- main path ----
    // Fully-valid i-blocks may skip compute for tiles with j0 >= len (p == 0 exactly,
    // since mrun is finite after the always-valid early tiles). Mixed boundary blocks
    // process everything so padded rows keep the uniform-softmax semantics.
    const bool full_i = (i0 + IT <= len);
    const int  jlim   = full_i ? ((len + JT - 1) & ~(JT - 1)) : SLEN;
    const bool vi     = iG_lane < len;

    bfx8 qfrag[2];
#pragma unroll
    for (int c = 0; c < 2; ++c)
        qfrag[c] = *(const bfx8*)(Qb + (size_t)iG_lane * DH + c * 32 + qd * 8);

    // preload K tile 0
    bfx8 kf[4][2];
#pragma unroll
    for (int t4 = 0; t4 < 4; ++t4)
#pragma unroll
        for (int c = 0; c < 2; ++c)
            kf[t4][c] = *(const bfx8*)(Kb + (size_t)(t4 * 16 + m) * DH + c * 32 + qd * 8);

    float mrun = -3.0e38f, lrun = 0.f;

    for (int j0 = 0; j0 < jlim; j0 += JT) {
        // ---- S^T = K Q^T ----
        f32x4 sacc[4];
#pragma unroll
        for (int t4 = 0; t4 < 4; ++t4) {
            sacc[t4] = (f32x4){0.f, 0.f, 0.f, 0.f};
#pragma unroll
            for (int c = 0; c < 2; ++c)
                sacc[t4] = __builtin_amdgcn_mfma_f32_16x16x32_bf16(kf[t4][c], qfrag[c], sacc[t4], 0, 0, 0);
        }

        // ---- V frags issued early: softmax hides their latency ----
        bfx8 vf[2][4];
#pragma unroll
        for (int kc = 0; kc < 2; ++kc)
#pragma unroll
            for (int c = 0; c < 4; ++c)
                vf[kc][c] = *(const bfx8*)(Vb + (size_t)(c * 16 + m) * SLEN + j0 + kc * 32 + qd * 8);

        // ---- prefetch next K tile (clamped; overshoot loads are harmless) ----
        {
            const int jn = (j0 + JT < SLEN) ? (j0 + JT) : 0;
#pragma unroll
            for (int t4 = 0; t4 < 4; ++t4)
#pragma unroll
                for (int c = 0; c < 2; ++c)
                    kf[t4][c] = *(const bfx8*)(Kb + (size_t)(jn + t4 * 16 + m) * DH + c * 32 + qd * 8);
        }

        // ---- mask + scale + vectorized logits store ----
        float ls[4][4];
#pragma unroll
        for (int t4 = 0; t4 < 4; ++t4) {
            f32x4 lv;
#pragma unroll
            for (int r = 0; r < 4; ++r) {
                const int jG = j0 + t4 * 16 + qd * 4 + r;
                const bool ok = vi && (jG < len);
                lv[r] = ok ? sacc[t4][r] * 0.125f : -1.0e10f;
                ls[t4][r] = lv[r];
            }
            __builtin_nontemporal_store(lv, (f32x4*)(lrow + j0 + t4 * 16 + qd * 4));
        }

        // ---- online softmax: 16 in-register values + 2 shfl_xor per reduce ----
        float smax = ls[0][0];
#pragma unroll
        for (int t4 = 0; t4 < 4; ++t4)
#pragma unroll
            for (int r = 0; r < 4; ++r) smax = fmaxf(smax, ls[t4][r]);
        smax = fmaxf(smax, __shfl_xor(smax, 16));
        smax = fmaxf(smax, __shfl_xor(smax, 32));
        const float mn = fmaxf(mrun, smax);
        const float al = __expf(mrun - mn);
        float psum = 0.f;
        union { __bf16 h[4]; uint2 u; } pk[4];
#pragma unroll
        for (int t4 = 0; t4 < 4; ++t4)
#pragma unroll
            for (int r = 0; r < 4; ++r) {
                const float p = __expf(ls[t4][r] - mn);
                psum += p;
                pk[t4].h[r] = (__bf16)p;
            }
        psum += __shfl_xor(psum, 16);
        psum += __shfl_xor(psum, 32);
        lrun = lrun * al + psum;
        mrun = mn;

        // P -> per-wave LDS (4x 8B writes; DS ops are in-order per wave)
#pragma unroll
        for (int t4 = 0; t4 < 4; ++t4)
            *(uint2*)(myP + m * LDP + t4 * 16 + qd * 4) = pk[t4].u;

        // ---- rescale acc: rows qd*4+r need al of that row (held by lane qd*4+r) ----
#pragma unroll
        for (int r = 0; r < 4; ++r) {
            const float alr = __shfl(al, qd * 4 + r);
#pragma unroll
            for (int c = 0; c < 4; ++c) acc[c][r] *= alr;
        }

        // ---- PV ----
#pragma unroll
        for (int kc = 0; kc < 2; ++kc) {
            const bfx8 pf = *(const bfx8*)&myP[m * LDP + kc * 32 + qd * 8];
#pragma unroll
            for (int c = 0; c < 4; ++c)
                acc[c] = __builtin_amdgcn_mfma_f32_16x16x32_bf16(pf, vf[kc][c], acc[c], 0, 0, 0);
        }
    }

    // ---- masked-j tail: constant stores only (p == 0 exactly for these tiles) ----
    for (int j0 = jlim; j0 < SLEN; j0 += JT)
#pragma unroll
        for (int t4 = 0; t4 < 4; ++t4)
            __builtin_nontemporal_store(NEG4, (f32x4*)(lrow + j0 + t4 * 16 + qd * 4));

    // ---- epilogue: x = acc / l (lrun of row qd*4+r held by lane qd*4+r) ----
#pragma unroll
    for (int r = 0; r < 4; ++r) {
        const float lr  = __shfl(lrun, qd * 4 + r);
        const float inv = 1.0f / lr;
        const int   iG  = i0 + wave * 16 + qd * 4 + r;
#pragma unroll
        for (int c = 0; c < 4; ++c)
            out_x[((size_t)bh * SLEN + iG) * DH + c * 16 + m] = acc[c][r] * inv;
    }
}

extern "C" void kernel_launch(void* const* d_in, const int* in_sizes, int n_in,
                              void* d_out, int out_size, void* d_ws, size_t ws_size,
                              hipStream_t stream) {
    const float* qkv     = (const float*)d_in[0];
    const float* cosb    = (const float*)d_in[1];
    const float* sinb    = (const float*)d_in[2];
    const int*   seqlens = (const int*)d_in[3];
    float* out_x      = (float*)d_out;
    float* out_logits = out_x + (size_t)NB * NH * SLEN * DH;

    const size_t perT = (size_t)NB * NH * SLEN * DH;
    __bf16* Qr = (__bf16*)d_ws;
    __bf16* Kr = Qr + perT;
    __bf16* Vt = Kr + perT;

    dim3 block(256);
    ddit_prep<<<dim3(NB * NH * (SLEN / 64)), block, 0, stream>>>(qkv, cosb, sinb, Qr, Kr, Vt);
    ddit_attn<<<dim3(NB * NH * (SLEN / IT)), block, 0, stream>>>(Qr, Kr, Vt, seqlens, out_x, out_logits);
}

// Round 2
// 561.617 us; speedup vs baseline: 1.0346x; 1.0094x over previous
//
#include <hip/hip_runtime.h>
#include <hip/hip_bf16.h>
#include <math.h>

// Problem constants (B,S,H,D fixed by the reference setup_inputs)
#define SLEN 2048
#define NH   12
#define NB   2
#define DH   64
#define IT   64          // i-rows per block
#define JT   64          // j-cols per tile
#define NWAVE 4
#define LDP  72          // P-buffer row stride (bf16 elems); 72*2B keeps 16B align
#define LDL  68          // logits staging stride (f32); +4 pad -> 2-way banks (free)

typedef __bf16 bfx8 __attribute__((ext_vector_type(8)));
typedef float  f32x4 __attribute__((ext_vector_type(4)));

// ---------------- pass 1: rotary + bf16 cast + V transpose ----------------
__global__ __launch_bounds__(256)
void ddit_prep(const float* __restrict__ qkv,
               const float* __restrict__ cosb,
               const float* __restrict__ sinb,
               __bf16* __restrict__ Qr, __bf16* __restrict__ Kr,
               __bf16* __restrict__ Vt)
{
    __shared__ __align__(16) __bf16 Vlds[64 * LDP];
    const int tid = threadIdx.x;
    const int nS  = SLEN / 64;
    const int s0  = (blockIdx.x % nS) * 64;
    const int bh  = blockIdx.x / nS;
    const int h   = bh % NH;
    const int b   = bh / NH;
    const int r   = tid >> 2;          // 0..63 row (s offset)
    const int d0  = (tid & 3) * 16;    // 16 d per thread
    const int s   = s0 + r;

#pragma unroll
    for (int t = 0; t < 2; ++t) {
        const float* src = qkv + (((size_t)((size_t)b * SLEN + s) * 3 + t) * NH + h) * DH;
        const float* cs  = cosb + ((size_t)s * 3 + t) * DH;
        const float* sn  = sinb + ((size_t)s * 3 + t) * DH;
        union { __bf16 hv[16]; uint4 u4[2]; } pk;
#pragma unroll
        for (int dd = 0; dd < 16; dd += 4) {
            const int d = d0 + dd;
            float4 f  = *(const float4*)(src + d);
            float4 g  = *(const float4*)(src + (d ^ 32));
            float4 c4 = *(const float4*)(cs + d);
            float4 s4 = *(const float4*)(sn + d);
            const float sg = (d < 32) ? -1.f : 1.f;
            pk.hv[dd + 0] = (__bf16)(f.x * c4.x + sg * g.x * s4.x);
            pk.hv[dd + 1] = (__bf16)(f.y * c4.y + sg * g.y * s4.y);
            pk.hv[dd + 2] = (__bf16)(f.z * c4.z + sg * g.z * s4.z);
            pk.hv[dd + 3] = (__bf16)(f.w * c4.w + sg * g.w * s4.w);
        }
        __bf16* dst = (t == 0 ? Qr : Kr) + ((size_t)bh * SLEN + s) * DH + d0;
        *(uint4*)(dst + 0) = pk.u4[0];
        *(uint4*)(dst + 8) = pk.u4[1];
    }

    {
        const float* src = qkv + (((size_t)((size_t)b * SLEN + s) * 3 + 2) * NH + h) * DH;
#pragma unroll
        for (int dd = 0; dd < 16; dd += 4) {
            float4 f = *(const float4*)(src + d0 + dd);
            union { __bf16 hv[4]; uint2 u; } pk;
            pk.hv[0] = (__bf16)f.x; pk.hv[1] = (__bf16)f.y;
            pk.hv[2] = (__bf16)f.z; pk.hv[3] = (__bf16)f.w;
            *(uint2*)(Vlds + r * LDP + d0 + dd) = pk.u;
        }
    }
    __syncthreads();
    {
        const int dv   = tid >> 2;
        const int soff = (tid & 3) * 16;
        union { __bf16 hv[16]; uint4 u4[2]; } pk;
#pragma unroll
        for (int j = 0; j < 16; ++j)
            pk.hv[j] = Vlds[(soff + j) * LDP + dv];
        __bf16* dst = Vt + ((size_t)bh * DH + dv) * SLEN + s0 + soff;
        *(uint4*)(dst + 0) = pk.u4[0];
        *(uint4*)(dst + 8) = pk.u4[1];
    }
}

// ---------------- pass 2: barrier-free fused attention (swapped QK^T) ----------------
// mfma(K,Q): D[col=lane&15 = q-row i][row=(lane>>4)*4+reg = j-local].
// Logits are staged per-wave in LDS and flushed with 4-rows-x-256B-contiguous
// store instructions (16 consecutive lanes = one full row chunk) instead of
// 16-rows-x-64B scatter: 4x longer DRAM bursts, 4x fewer concurrent row streams.
__global__ __launch_bounds__(256)
void ddit_attn(const __bf16* __restrict__ Qr,
               const __bf16* __restrict__ Kr,
               const __bf16* __restrict__ Vt,
               const int*   __restrict__ seqlens,
               float* __restrict__ out_x,
               float* __restrict__ out_logits)
{
    __shared__ __align__(16) __bf16 Pbuf[NWAVE * 16 * LDP]; // per-wave, no barrier needed
    __shared__ __align__(16) float  Lbuf[NWAVE * 16 * LDL]; // per-wave logits staging

    const int tid  = threadIdx.x;
    const int wave = tid >> 6;
    const int lane = tid & 63;
    const int qd   = lane >> 4;   // quad 0..3
    const int m    = lane & 15;

    // XCD swizzle: keep all 32 i-blocks of one bh on the same XCD (L2 locality)
    const int nIt   = SLEN / IT;                    // 32
    const int gridN = NB * NH * nIt;                // 768
    const int bid   = blockIdx.x;
    const int nid   = (bid & 7) * (gridN >> 3) + (bid >> 3);
    const int it    = nid % nIt;
    const int bh    = nid / nIt;
    const int b     = bh / NH;
    const int i0    = it * IT;
    const int len   = seqlens[b];

    const __bf16* Qb = Qr + (size_t)bh * SLEN * DH;
    const __bf16* Kb = Kr + (size_t)bh * SLEN * DH;
    const __bf16* Vb = Vt + (size_t)bh * DH * SLEN;

    const int iG_lane = i0 + wave * 16 + m;       // this lane's q-row
    // per-wave logits base: wave owns i-rows [i0+wave*16, +16)
    float* lbase = out_logits + (size_t)bh * SLEN * SLEN + (size_t)(i0 + wave * 16) * SLEN;
    __bf16* myP = Pbuf + wave * 16 * LDP;
    float*  myL = Lbuf + wave * 16 * LDL;

    f32x4 acc[4];
#pragma unroll
    for (int c = 0; c < 4; ++c) acc[c] = (f32x4){0.f, 0.f, 0.f, 0.f};
    const f32x4 NEG4 = (f32x4){-1.0e10f, -1.0e10f, -1.0e10f, -1.0e10f};

    // ---- fast path: fully padded i-block ----
    // All logits -1e10; reference softmax over an all-masked row is uniform,
    // so x = mean over ALL 2048 v rows. Do PV with P==1, skip K/QK/softmax.
    if (i0 >= len) {
        union { __bf16 h[4]; uint2 u; } ones;
#pragma unroll
        for (int r = 0; r < 4; ++r) ones.h[r] = (__bf16)1.0f;
#pragma unroll
        for (int t4 = 0; t4 < 4; ++t4)
            *(uint2*)(myP + m * LDP + t4 * 16 + qd * 4) = ones.u;
        bfx8 pf1[2];
#pragma unroll
        for (int kc = 0; kc < 2; ++kc)
            pf1[kc] = *(const bfx8*)&myP[m * LDP + kc * 32 + qd * 8];

        for (int j0 = 0; j0 < SLEN; j0 += JT) {
            bfx8 vf[2][4];
#pragma unroll
            for (int kc = 0; kc < 2; ++kc)
#pragma unroll
                for (int c = 0; c < 4; ++c)
                    vf[kc][c] = *(const bfx8*)(Vb + (size_t)(c * 16 + m) * SLEN + j0 + kc * 32 + qd * 8);
            // coalesced constant logits: 4 instrs, each 4 rows x 256B contiguous
#pragma unroll
            for (int k2 = 0; k2 < 4; ++k2)
                __builtin_nontemporal_store(NEG4,
                    (f32x4*)(lbase + (size_t)(k2 * 4 + qd) * SLEN + j0 + m * 4));
#pragma unroll
            for (int kc = 0; kc < 2; ++kc)
#pragma unroll
                for (int c = 0; c < 4; ++c)
                    acc[c] = __builtin_amdgcn_mfma_f32_16x16x32_bf16(pf1[kc], vf[kc][c], acc[c], 0, 0, 0);
        }
        const float inv = 1.0f / (float)SLEN;
#pragma unroll
        for (int r = 0; r < 4; ++r) {
            const int iG = i0 + wave * 16 + qd * 4 + r;
#pragma unroll
            for (int c = 0; c < 4; ++c)
                out_x[((size_t)bh * SLEN + iG) * DH + c * 16 + m] = acc[c][r] * inv;
        }
        return;
    }

    // ---- main path ----
    const bool full_i = (i0 + IT <= len);
    const int  jlim   = full_i ? ((len + JT - 1) & ~(JT - 1)) : SLEN;
    const bool vi     = iG_lane < len;

    bfx8 qfrag[2];
#pragma unroll
    for (int c = 0; c < 2; ++c)
        qfrag[c] = *(const bfx8*)(Qb + (size_t)iG_lane * DH + c * 32 + qd * 8);

    // preload K tile 0
    bfx8 kf[4][2];
#pragma unroll
    for (int t4 = 0; t4 < 4; ++t4)
#pragma unroll
        for (int c = 0; c < 2; ++c)
            kf[t4][c] = *(const bfx8*)(Kb + (size_t)(t4 * 16 + m) * DH + c * 32 + qd * 8);

    float mrun = -3.0e38f, lrun = 0.f;

    for (int j0 = 0; j0 < jlim; j0 += JT) {
        // ---- S^T = K Q^T ----
        f32x4 sacc[4];
#pragma unroll
        for (int t4 = 0; t4 < 4; ++t4) {
            sacc[t4] = (f32x4){0.f, 0.f, 0.f, 0.f};
#pragma unroll
            for (int c = 0; c < 2; ++c)
                sacc[t4] = __builtin_amdgcn_mfma_f32_16x16x32_bf16(kf[t4][c], qfrag[c], sacc[t4], 0, 0, 0);
        }

        // ---- V frags issued early: softmax hides their latency ----
        bfx8 vf[2][4];
#pragma unroll
        for (int kc = 0; kc < 2; ++kc)
#pragma unroll
            for (int c = 0; c < 4; ++c)
                vf[kc][c] = *(const bfx8*)(Vb + (size_t)(c * 16 + m) * SLEN + j0 + kc * 32 + qd * 8);

        // ---- prefetch next K tile (clamped; overshoot loads are harmless) ----
        {
            const int jn = (j0 + JT < SLEN) ? (j0 + JT) : 0;
#pragma unroll
            for (int t4 = 0; t4 < 4; ++t4)
#pragma unroll
                for (int c = 0; c < 2; ++c)
                    kf[t4][c] = *(const bfx8*)(Kb + (size_t)(jn + t4 * 16 + m) * DH + c * 32 + qd * 8);
        }

        // ---- mask + scale; stage logits tile to per-wave LDS ----
        float ls[4][4];
#pragma unroll
        for (int t4 = 0; t4 < 4; ++t4) {
            f32x4 lv;
#pragma unroll
            for (int r = 0; r < 4; ++r) {
                const int jG = j0 + t4 * 16 + qd * 4 + r;
                const bool ok = vi && (jG < len);
                lv[r] = ok ? sacc[t4][r] * 0.125f : -1.0e10f;
                ls[t4][r] = lv[r];
            }
            *(f32x4*)&myL[m * LDL + t4 * 16 + qd * 4] = lv;
        }

        // ---- online softmax: 16 in-register values + 2 shfl_xor per reduce ----
        float smax = ls[0][0];
#pragma unroll
        for (int t4 = 0; t4 < 4; ++t4)
#pragma unroll
            for (int r = 0; r < 4; ++r) smax = fmaxf(smax, ls[t4][r]);
        smax = fmaxf(smax, __shfl_xor(smax, 16));
        smax = fmaxf(smax, __shfl_xor(smax, 32));
        const float mn = fmaxf(mrun, smax);
        const float al = __expf(mrun - mn);
        float psum = 0.f;
        union { __bf16 h[4]; uint2 u; } pk[4];
#pragma unroll
        for (int t4 = 0; t4 < 4; ++t4)
#pragma unroll
            for (int r = 0; r < 4; ++r) {
                const float p = __expf(ls[t4][r] - mn);
                psum += p;
                pk[t4].h[r] = (__bf16)p;
            }
        psum += __shfl_xor(psum, 16);
        psum += __shfl_xor(psum, 32);
        lrun = lrun * al + psum;
        mrun = mn;

        // P -> per-wave LDS (4x 8B writes; DS ops are in-order per wave)
#pragma unroll
        for (int t4 = 0; t4 < 4; ++t4)
            *(uint2*)(myP + m * LDP + t4 * 16 + qd * 4) = pk[t4].u;

        // ---- rescale acc: rows qd*4+r need al of that row (held by lane qd*4+r) ----
#pragma unroll
        for (int r = 0; r < 4; ++r) {
            const float alr = __shfl(al, qd * 4 + r);
#pragma unroll
            for (int c = 0; c < 4; ++c) acc[c][r] *= alr;
        }

        // ---- coalesced logits flush: 4 instrs, each 4 rows x 256B contiguous ----
        // (DS in-order per wave: these reads see this tile's myL writes.
        //  NT stores issue here and drain under the PV MFMAs below.)
        {
            float* Lt = lbase + j0;
#pragma unroll
            for (int k2 = 0; k2 < 4; ++k2) {
                const f32x4 t = *(const f32x4*)&myL[(k2 * 4 + qd) * LDL + m * 4];
                __builtin_nontemporal_store(t, (f32x4*)(Lt + (size_t)(k2 * 4 + qd) * SLEN + m * 4));
            }
        }

        // ---- PV ----
#pragma unroll
        for (int kc = 0; kc < 2; ++kc) {
            const bfx8 pf = *(const bfx8*)&myP[m * LDP + kc * 32 + qd * 8];
#pragma unroll
            for (int c = 0; c < 4; ++c)
                acc[c] = __builtin_amdgcn_mfma_f32_16x16x32_bf16(pf, vf[kc][c], acc[c], 0, 0, 0);
        }
    }

    // ---- masked-j tail: coalesced constant stores (p == 0 exactly for these tiles) ----
    for (int j0 = jlim; j0 < SLEN; j0 += JT)
#pragma unroll
        for (int k2 = 0; k2 < 4; ++k2)
            __builtin_nontemporal_store(NEG4,
                (f32x4*)(lbase + (size_t)(k2 * 4 + qd) * SLEN + j0 + m * 4));

    // ---- epilogue: x = acc / l (lrun of row qd*4+r held by lane qd*4+r) ----
#pragma unroll
    for (int r = 0; r < 4; ++r) {
        const float lr  = __shfl(lrun, qd * 4 + r);
        const float inv = 1.0f / lr;
        const int   iG  = i0 + wave * 16 + qd * 4 + r;
#pragma unroll
        for (int c = 0; c < 4; ++c)
            out_x[((size_t)bh * SLEN + iG) * DH + c * 16 + m] = acc[c][r] * inv;
    }
}

extern "C" void kernel_launch(void* const* d_in, const int* in_sizes, int n_in,
                              void* d_out, int out_size, void* d_ws, size_t ws_size,
                              hipStream_t stream) {
    const float* qkv     = (const float*)d_in[0];
    const float* cosb    = (const float*)d_in[1];
    const float* sinb    = (const float*)d_in[2];
    const int*   seqlens = (const int*)d_in[3];
    float* out_x      = (float*)d_out;
    float* out_logits = out_x + (size_t)NB * NH * SLEN * DH;

    const size_t perT = (size_t)NB * NH * SLEN * DH;
    __bf16* Qr = (__bf16*)d_ws;
    __bf16* Kr = Qr + perT;
    __bf16* Vt = Kr + perT;

    dim3 block(256);
    ddit_prep<<<dim3(NB * NH * (SLEN / 64)), block, 0, stream>>>(qkv, cosb, sinb, Qr, Kr, Vt);
    ddit_attn<<<dim3(NB * NH * (SLEN / IT)), block, 0, stream>>>(Qr, Kr, Vt, seqlens, out_x, out_logits);
}